// Round 10
// baseline (91.064 us; speedup 1.0000x reference)
//
#include <hip/hip_runtime.h>
#include <math.h>

// ---------------------------------------------------------------------------
// DRR forward projection: per-pixel ray march through D^3 volume, trilinear.
//
// setup_k: folds all small linear algebra into 21 per-batch floats:
//   vox(s) = p0 + alpha_s*(A1@pixh), ray = A2@pixh, seglen = |ray|/S.
//
// drr9 == drr8 (wall 38.3us, profiled 47.2, addr model floor 41us) + ONE
// change: the 4 gathers of each unrolled slot are PREDICATED on s<=shi
// (q zeroed otherwise -> contribution exactly 0, no act gate needed).
// ~13.5% of slots are beyond the slab-clipped range; skipping their loads
// removes that fraction of TA addresses. Near-wave-uniform branch (4
// adjacent pixels/wave): dead iterations skip via execz, boundary iteration
// issues under partial exec mask.
//   - 1 wave = 4 pixels (1x4 strip), 16 lanes/pixel striding over steps
//   - analytic slab clip to the (-1,D) support box (outside = exact 0)
//   - phase-split 6x4 pair-gathers (no fence; r6 showed fence => scratch)
//   - z-corner pair as one 8B load (clamped base + branchless select)
//   - x/y out-of-bounds folded into lerp weights (matches reference inb)
//   - XCD-aware 64x64-pixel supertile swizzle (halved FETCH_SIZE in r3)
// ---------------------------------------------------------------------------

typedef float f2 __attribute__((ext_vector_type(2), aligned(4)));

__device__ __forceinline__ void inv4x4(const float* m, float* inv) {
    inv[0]  =  m[5]*m[10]*m[15] - m[5]*m[11]*m[14] - m[9]*m[6]*m[15] + m[9]*m[7]*m[14] + m[13]*m[6]*m[11] - m[13]*m[7]*m[10];
    inv[4]  = -m[4]*m[10]*m[15] + m[4]*m[11]*m[14] + m[8]*m[6]*m[15] - m[8]*m[7]*m[14] - m[12]*m[6]*m[11] + m[12]*m[7]*m[10];
    inv[8]  =  m[4]*m[9]*m[15]  - m[4]*m[11]*m[13] - m[8]*m[5]*m[15] + m[8]*m[7]*m[13] + m[12]*m[5]*m[11] - m[12]*m[7]*m[9];
    inv[12] = -m[4]*m[9]*m[14]  + m[4]*m[10]*m[13] + m[8]*m[5]*m[14] - m[8]*m[6]*m[13] - m[12]*m[5]*m[10] + m[12]*m[6]*m[9];
    inv[1]  = -m[1]*m[10]*m[15] + m[1]*m[11]*m[14] + m[9]*m[2]*m[15] - m[9]*m[3]*m[14] - m[13]*m[2]*m[11] + m[13]*m[3]*m[10];
    inv[5]  =  m[0]*m[10]*m[15] - m[0]*m[11]*m[14] - m[8]*m[2]*m[15] + m[8]*m[3]*m[14] + m[12]*m[2]*m[11] - m[12]*m[3]*m[10];
    inv[9]  = -m[0]*m[9]*m[15]  + m[0]*m[11]*m[13] + m[8]*m[1]*m[15] - m[8]*m[3]*m[13] - m[12]*m[1]*m[11] + m[12]*m[3]*m[9];
    inv[13] =  m[0]*m[9]*m[14]  - m[0]*m[10]*m[13] - m[8]*m[1]*m[14] + m[8]*m[2]*m[13] + m[12]*m[1]*m[10] - m[12]*m[2]*m[9];
    inv[2]  =  m[1]*m[6]*m[15]  - m[1]*m[7]*m[14]  - m[5]*m[2]*m[15] + m[5]*m[3]*m[14] + m[13]*m[2]*m[7]  - m[13]*m[3]*m[6];
    inv[6]  = -m[0]*m[6]*m[15]  + m[0]*m[7]*m[14]  + m[4]*m[2]*m[15] - m[4]*m[3]*m[14] - m[12]*m[2]*m[7]  + m[12]*m[3]*m[6];
    inv[10] =  m[0]*m[5]*m[15]  - m[0]*m[7]*m[13]  - m[4]*m[1]*m[15] + m[4]*m[3]*m[13] + m[12]*m[1]*m[7]  - m[12]*m[3]*m[5];
    inv[14] = -m[0]*m[5]*m[14]  + m[0]*m[6]*m[13]  + m[4]*m[1]*m[14] - m[4]*m[2]*m[13] - m[12]*m[1]*m[6]  + m[12]*m[2]*m[5];
    inv[3]  = -m[1]*m[6]*m[11]  + m[1]*m[7]*m[10]  + m[5]*m[2]*m[11] - m[5]*m[3]*m[10] - m[9]*m[2]*m[7]   + m[9]*m[3]*m[6];
    inv[7]  =  m[0]*m[6]*m[11]  - m[0]*m[7]*m[10]  - m[4]*m[2]*m[11] + m[4]*m[3]*m[10] + m[8]*m[2]*m[7]   - m[8]*m[3]*m[6];
    inv[11] = -m[0]*m[5]*m[11]  + m[0]*m[7]*m[9]   + m[4]*m[1]*m[11] - m[4]*m[3]*m[9]  - m[8]*m[1]*m[7]   + m[8]*m[3]*m[5];
    inv[15] =  m[0]*m[5]*m[10]  - m[0]*m[6]*m[9]   - m[4]*m[1]*m[10] + m[4]*m[2]*m[9]  + m[8]*m[1]*m[6]   - m[8]*m[2]*m[5];
    float det = m[0]*inv[0] + m[1]*inv[4] + m[2]*inv[8] + m[3]*inv[12];
    float rd = 1.0f/det;
    for (int k = 0; k < 16; ++k) inv[k] *= rd;
}

// Per-batch params: P[b*24 + 0..8]=A1, [9..17]=A2, [18..20]=p0
__global__ void setup_k(const float* __restrict__ rt_inv, const float* __restrict__ k_inv,
                        const float* __restrict__ sdd,    const float* __restrict__ iso,
                        const float* __restrict__ affine, const float* __restrict__ rot,
                        const float* __restrict__ xyz,    float* __restrict__ P, int B)
{
    int b = blockIdx.x * blockDim.x + threadIdx.x;
    if (b >= B) return;

    const float* Mi = rt_inv + (size_t)b * 16;
    float rt[16];
    inv4x4(Mi, rt);

    float c[3];
    for (int r = 0; r < 3; ++r)
        c[r] = rt[r*4+0]*iso[0] + rt[r*4+1]*iso[1] + rt[r*4+2]*iso[2] + rt[r*4+3];

    float rx = rot[b*3+0], ry = rot[b*3+1], rz = rot[b*3+2];
    float th = sqrtf(rx*rx + ry*ry + rz*rz);
    float Rr[9];
    if (th < 1e-8f) {
        Rr[0]=1.f; Rr[1]=0.f; Rr[2]=0.f;
        Rr[3]=0.f; Rr[4]=1.f; Rr[5]=0.f;
        Rr[6]=0.f; Rr[7]=0.f; Rr[8]=1.f;
    } else {
        float kx = rx/th, ky = ry/th, kz = rz/th;
        float s = sinf(th), ct = cosf(th), v = 1.f - ct;
        Rr[0] = ct + v*kx*kx;     Rr[1] = v*kx*ky - s*kz;  Rr[2] = v*kx*kz + s*ky;
        Rr[3] = v*ky*kx + s*kz;   Rr[4] = ct + v*ky*ky;    Rr[5] = v*ky*kz - s*kx;
        Rr[6] = v*kz*kx - s*ky;   Rr[7] = v*kz*ky + s*kx;  Rr[8] = ct + v*kz*kz;
    }

    float tp[3];
    for (int r = 0; r < 3; ++r)
        tp[r] = c[r] + xyz[b*3+r] - (Rr[r*3+0]*c[0] + Rr[r*3+1]*c[1] + Rr[r*3+2]*c[2]);

    float G[9], t[3];
    for (int r = 0; r < 3; ++r) {
        for (int cc = 0; cc < 3; ++cc)
            G[r*3+cc] = Mi[r*4+0]*Rr[0*3+cc] + Mi[r*4+1]*Rr[1*3+cc] + Mi[r*4+2]*Rr[2*3+cc];
        t[r] = Mi[r*4+0]*tp[0] + Mi[r*4+1]*tp[1] + Mi[r*4+2]*tp[2] + Mi[r*4+3];
    }

    float Ai[16];
    inv4x4(affine, Ai);

    float p0[3];
    for (int r = 0; r < 3; ++r)
        p0[r] = Ai[r*4+0]*t[0] + Ai[r*4+1]*t[1] + Ai[r*4+2]*t[2] + Ai[r*4+3];

    float MG[9];
    for (int r = 0; r < 3; ++r)
        for (int cc = 0; cc < 3; ++cc)
            MG[r*3+cc] = Ai[r*4+0]*G[0*3+cc] + Ai[r*4+1]*G[1*3+cc] + Ai[r*4+2]*G[2*3+cc];

    const float* Ki = k_inv + (size_t)b * 9;
    float sd = sdd[b];
    float* Pb = P + (size_t)b * 24;
    for (int r = 0; r < 3; ++r)
        for (int cc = 0; cc < 3; ++cc) {
            Pb[r*3+cc]     = (MG[r*3+0]*Ki[0*3+cc] + MG[r*3+1]*Ki[1*3+cc] + MG[r*3+2]*Ki[2*3+cc]) * sd;
            Pb[9 + r*3+cc] = (G[r*3+0]*Ki[0*3+cc]  + G[r*3+1]*Ki[1*3+cc]  + G[r*3+2]*Ki[2*3+cc])  * sd;
        }
    Pb[18] = p0[0]; Pb[19] = p0[1]; Pb[20] = p0[2];
}

// 1 wave = 4 pixels (1x4 strip); lane = 16*p + t; lane t strides steps.
// Block (256 thr, 4 waves) owns a 4x4 pixel patch; 256 blocks = one 64x64
// supertile; supertiles chunked per XCD.
__global__ void __launch_bounds__(256, 6) drr9(
        const float* __restrict__ vol, const float* __restrict__ P,
        float* __restrict__ out,
        const int* __restrict__ Hp, const int* __restrict__ Wp, const int* __restrict__ Sp,
        int B, int D)
{
    const int H = *Hp, W = *Wp, S = *Sp;
    const int npix = H * W;
    const int nSj = (W + 63) >> 6, nSi = (H + 63) >> 6;
    const int nS = nSi * nSj;
    const int nStot = B * nS;
    const long long nVB = (long long)nStot << 8;   // 256 blocks per supertile

    const int tid  = threadIdx.x;
    const int wave = tid >> 6, lane = tid & 63;
    const int p    = lane >> 4, t = lane & 15;
    const int D1   = D - 1;
    const float Sf = (float)S, invS = 1.0f / Sf;

    for (long long vb = blockIdx.x; vb < nVB; vb += gridDim.x) {
        int st, within;
        if ((nStot & 7) == 0) {
            int xcd = (int)(vb & 7);
            long long slot = vb >> 3;
            st = xcd * (nStot >> 3) + (int)(slot >> 8);
            within = (int)(slot & 255);
        } else {
            st = (int)(vb >> 8);
            within = (int)(vb & 255);
        }
        int b = 0, stl = st;
        if (B > 1) { b = st / nS; stl = st - b * nS; }
        int si = stl / nSj, sj = stl - si * nSj;

        int r0 = (si << 6) + ((within >> 4) << 2) + wave;   // row
        int c0 = (sj << 6) + ((within & 15) << 2) + p;      // col
        bool valid = (r0 < H) && (c0 < W);
        int rr = min(r0, H - 1), cc = min(c0, W - 1);

        const float* Pb = P + 24 * __builtin_amdgcn_readfirstlane(b);
        float px = cc + 0.5f, py = rr + 0.5f;
        float ddx = fmaf(Pb[0], px, fmaf(Pb[1], py, Pb[2]));
        float ddy = fmaf(Pb[3], px, fmaf(Pb[4], py, Pb[5]));
        float ddz = fmaf(Pb[6], px, fmaf(Pb[7], py, Pb[8]));
        float rxx = fmaf(Pb[9], px, fmaf(Pb[10], py, Pb[11]));
        float ryy = fmaf(Pb[12], px, fmaf(Pb[13], py, Pb[14]));
        float rzz = fmaf(Pb[15], px, fmaf(Pb[16], py, Pb[17]));
        float p0x = Pb[18], p0y = Pb[19], p0z = Pb[20];

        float seglen = sqrtf(rxx*rxx + ryy*ryy + rzz*rzz) * invS;

        // slab clip to support box (-1, D), widened
        const float lo = -1.001f, hi = (float)D + 0.001f;
        float a0 = 0.f, a1 = 1.f;
        {
            float pp[3] = {p0x, p0y, p0z};
            float dd[3] = {ddx, ddy, ddz};
            #pragma unroll
            for (int ax = 0; ax < 3; ++ax) {
                if (fabsf(dd[ax]) > 1e-12f) {
                    float r  = 1.0f / dd[ax];
                    float t0 = (lo - pp[ax]) * r;
                    float t1 = (hi - pp[ax]) * r;
                    a0 = fmaxf(a0, fminf(t0, t1));
                    a1 = fminf(a1, fmaxf(t0, t1));
                } else if (pp[ax] < lo || pp[ax] > hi) {
                    a1 = -1.0f;
                }
            }
        }
        int slo = (int)ceilf(a0 * Sf - 0.5f) - 1;
        int shi = (int)floorf(a1 * Sf - 0.5f) + 1;
        if (slo < 0) slo = 0;
        if (shi > S - 1) shi = S - 1;

        float sum = 0.f;

        // ---- phase-split main block: 6 samples/thread, loads predicated ----
        {
            f2    q[24];
            float xs[6], ys[6], zs[6];

            #pragma unroll
            for (int it = 0; it < 6; ++it) {
                int s = slo + t + (it << 4);
                float al = (s + 0.5f) * invS;
                float x = fmaf(al, ddx, p0x);
                float y = fmaf(al, ddy, p0y);
                float z = fmaf(al, ddz, p0z);
                xs[it] = x; ys[it] = y; zs[it] = z;
                if (s <= shi) {
                    int ix = (int)floorf(x), iy = (int)floorf(y), iz = (int)floorf(z);
                    int x0c = min(max(ix, 0), D1), x1c = min(max(ix + 1, 0), D1);
                    int y0c = min(max(iy, 0), D1), y1c = min(max(iy + 1, 0), D1);
                    int z0c = min(max(iz, 0), D - 2);
                    int a0r = x0c * D, a1r = x1c * D;
                    q[it*4+0] = *(const f2*)(vol + (unsigned)((a0r + y0c) * D + z0c));
                    q[it*4+1] = *(const f2*)(vol + (unsigned)((a0r + y1c) * D + z0c));
                    q[it*4+2] = *(const f2*)(vol + (unsigned)((a1r + y0c) * D + z0c));
                    q[it*4+3] = *(const f2*)(vol + (unsigned)((a1r + y1c) * D + z0c));
                } else {
                    q[it*4+0] = (f2){0.f, 0.f};
                    q[it*4+1] = (f2){0.f, 0.f};
                    q[it*4+2] = (f2){0.f, 0.f};
                    q[it*4+3] = (f2){0.f, 0.f};
                }
            }

            #pragma unroll
            for (int it = 0; it < 6; ++it) {
                float x = xs[it], y = ys[it], z = zs[it];
                float fx = floorf(x), fy = floorf(y), fz = floorf(z);
                int ix = (int)fx, iy = (int)fy, iz = (int)fz;
                float tx = x - fx, ty = y - fy, tz = z - fz;
                int z0c = min(max(iz, 0), D - 2);
                bool e0 = (iz == z0c), em = (iz == z0c - 1), ep = (iz == z0c + 1);
                f2 q00 = q[it*4+0], q01 = q[it*4+1], q10 = q[it*4+2], q11 = q[it*4+3];
                float v0, v1, c00, c01, c10, c11;
                v0 = e0 ? q00.x : (ep ? q00.y : 0.f);
                v1 = e0 ? q00.y : (em ? q00.x : 0.f);
                c00 = fmaf(tz, v1 - v0, v0);
                v0 = e0 ? q01.x : (ep ? q01.y : 0.f);
                v1 = e0 ? q01.y : (em ? q01.x : 0.f);
                c01 = fmaf(tz, v1 - v0, v0);
                v0 = e0 ? q10.x : (ep ? q10.y : 0.f);
                v1 = e0 ? q10.y : (em ? q10.x : 0.f);
                c10 = fmaf(tz, v1 - v0, v0);
                v0 = e0 ? q11.x : (ep ? q11.y : 0.f);
                v1 = e0 ? q11.y : (em ? q11.x : 0.f);
                c11 = fmaf(tz, v1 - v0, v0);
                float wy0 = ((unsigned)iy       < (unsigned)D) ? 1.f - ty : 0.f;
                float wy1 = ((unsigned)(iy + 1) < (unsigned)D) ? ty       : 0.f;
                float wx0 = ((unsigned)ix       < (unsigned)D) ? 1.f - tx : 0.f;
                float wx1 = ((unsigned)(ix + 1) < (unsigned)D) ? tx       : 0.f;
                float s0 = fmaf(wy0, c00, wy1 * c01);
                float s1 = fmaf(wy0, c10, wy1 * c11);
                // inactive slots have q==0 -> s0==s1==0 -> exact zero contribution
                sum = fmaf(wx0, s0, sum);
                sum = fmaf(wx1, s1, sum);
            }
        }

        // generic tail (never taken for paths <= 96 steps)
        for (int s = slo + 96 + t; s <= shi; s += 16) {
            float al = (s + 0.5f) * invS;
            float x = fmaf(al, ddx, p0x);
            float y = fmaf(al, ddy, p0y);
            float z = fmaf(al, ddz, p0z);
            float fx = floorf(x), fy = floorf(y), fz = floorf(z);
            int ix = (int)fx, iy = (int)fy, iz = (int)fz;
            float tx = x - fx, ty = y - fy, tz = z - fz;
            int x0c = min(max(ix, 0), D1), x1c = min(max(ix + 1, 0), D1);
            int y0c = min(max(iy, 0), D1), y1c = min(max(iy + 1, 0), D1);
            int z0c = min(max(iz, 0), D - 2);
            int a0r = x0c * D, a1r = x1c * D;
            f2 q00 = *(const f2*)(vol + (unsigned)((a0r + y0c) * D + z0c));
            f2 q01 = *(const f2*)(vol + (unsigned)((a0r + y1c) * D + z0c));
            f2 q10 = *(const f2*)(vol + (unsigned)((a1r + y0c) * D + z0c));
            f2 q11 = *(const f2*)(vol + (unsigned)((a1r + y1c) * D + z0c));
            bool e0 = (iz == z0c), em = (iz == z0c - 1), ep = (iz == z0c + 1);
            float v0, v1, c00, c01, c10, c11;
            v0 = e0 ? q00.x : (ep ? q00.y : 0.f);
            v1 = e0 ? q00.y : (em ? q00.x : 0.f);
            c00 = fmaf(tz, v1 - v0, v0);
            v0 = e0 ? q01.x : (ep ? q01.y : 0.f);
            v1 = e0 ? q01.y : (em ? q01.x : 0.f);
            c01 = fmaf(tz, v1 - v0, v0);
            v0 = e0 ? q10.x : (ep ? q10.y : 0.f);
            v1 = e0 ? q10.y : (em ? q10.x : 0.f);
            c10 = fmaf(tz, v1 - v0, v0);
            v0 = e0 ? q11.x : (ep ? q11.y : 0.f);
            v1 = e0 ? q11.y : (em ? q11.x : 0.f);
            c11 = fmaf(tz, v1 - v0, v0);
            float wy0 = ((unsigned)iy       < (unsigned)D) ? 1.f - ty : 0.f;
            float wy1 = ((unsigned)(iy + 1) < (unsigned)D) ? ty       : 0.f;
            float wx0 = ((unsigned)ix       < (unsigned)D) ? 1.f - tx : 0.f;
            float wx1 = ((unsigned)(ix + 1) < (unsigned)D) ? tx       : 0.f;
            float s0 = fmaf(wy0, c00, wy1 * c01);
            float s1 = fmaf(wy0, c10, wy1 * c11);
            sum = fmaf(wx0, s0, sum);
            sum = fmaf(wx1, s1, sum);
        }

        sum += __shfl_xor(sum, 8, 16);
        sum += __shfl_xor(sum, 4, 16);
        sum += __shfl_xor(sum, 2, 16);
        sum += __shfl_xor(sum, 1, 16);

        if (t == 0 && valid)
            out[(size_t)b * npix + (size_t)rr * W + cc] = sum * seglen;
    }
}

extern "C" void kernel_launch(void* const* d_in, const int* in_sizes, int n_in,
                              void* d_out, int out_size, void* d_ws, size_t ws_size,
                              hipStream_t stream)
{
    const float* volume = (const float*)d_in[0];
    const float* rt_inv = (const float*)d_in[1];
    const float* k_inv  = (const float*)d_in[2];
    const float* sdd    = (const float*)d_in[3];
    const float* iso    = (const float*)d_in[4];
    const float* affine = (const float*)d_in[5];
    const float* rot    = (const float*)d_in[6];
    const float* xyz    = (const float*)d_in[7];
    const int*   Hp     = (const int*)d_in[8];
    const int*   Wp     = (const int*)d_in[9];
    const int*   Sp     = (const int*)d_in[10];

    int B = in_sizes[1] / 16;                         // rt_inv is (B,4,4)
    int D = (int)lroundf(cbrtf((float)in_sizes[0]));  // volume is (D,D,D)

    float* P = (float*)d_ws;
    setup_k<<<(B + 63) / 64, 64, 0, stream>>>(rt_inv, k_inv, sdd, iso, affine, rot, xyz, P, B);

    // one block per 4x4-pixel patch via device-side supertile walk
    long long hw = (long long)out_size / B;
    long long vbl = (long long)B * ((hw + 4095) >> 12) * 256;
    if (vbl > (1 << 22)) vbl = (1 << 22);
    drr9<<<(int)vbl, 256, 0, stream>>>(volume, P, (float*)d_out, Hp, Wp, Sp, B, D);
    (void)n_in; (void)ws_size;
}

// Round 11
// 38.228 us; speedup vs baseline: 2.3821x; 2.3821x over previous
//
#include <hip/hip_runtime.h>
#include <math.h>

// ---------------------------------------------------------------------------
// DRR forward projection: per-pixel ray march through D^3 volume, trilinear.
//
// FINAL (= round-9 drr8, best measured: wall 38.3us, profiled 47.2).
// Structure is at the TA address-throughput floor for row-major layout:
// 4 row-addresses/sample x 25.2M lane-addresses ~= 41us model floor (87%
// efficiency measured). All levers tested: occupancy null (r9), forced-MLP
// spills (r6/r10), LDS staging regresses (r4/r7), quad-sharing regresses
// (r8). Dead-slot predication defeats SROA -> scratch (r10, WRITE 224MB).
//   - 1 wave = 4 pixels (1x4 strip), 16 lanes/pixel striding over steps
//   - analytic slab clip to the (-1,D) support box (outside = exact 0)
//   - phase-split 6x4 pair-gathers, unconditional writes (keeps q[] in VGPR)
//   - z-corner pair as one 8B load (clamped base + branchless select)
//   - x/y out-of-bounds folded into lerp weights (matches reference inb)
//   - XCD-aware 64x64-pixel supertile swizzle (halved FETCH_SIZE in r3)
// ---------------------------------------------------------------------------

typedef float f2 __attribute__((ext_vector_type(2), aligned(4)));

__device__ __forceinline__ void inv4x4(const float* m, float* inv) {
    inv[0]  =  m[5]*m[10]*m[15] - m[5]*m[11]*m[14] - m[9]*m[6]*m[15] + m[9]*m[7]*m[14] + m[13]*m[6]*m[11] - m[13]*m[7]*m[10];
    inv[4]  = -m[4]*m[10]*m[15] + m[4]*m[11]*m[14] + m[8]*m[6]*m[15] - m[8]*m[7]*m[14] - m[12]*m[6]*m[11] + m[12]*m[7]*m[10];
    inv[8]  =  m[4]*m[9]*m[15]  - m[4]*m[11]*m[13] - m[8]*m[5]*m[15] + m[8]*m[7]*m[13] + m[12]*m[5]*m[11] - m[12]*m[7]*m[9];
    inv[12] = -m[4]*m[9]*m[14]  + m[4]*m[10]*m[13] + m[8]*m[5]*m[14] - m[8]*m[6]*m[13] - m[12]*m[5]*m[10] + m[12]*m[6]*m[9];
    inv[1]  = -m[1]*m[10]*m[15] + m[1]*m[11]*m[14] + m[9]*m[2]*m[15] - m[9]*m[3]*m[14] - m[13]*m[2]*m[11] + m[13]*m[3]*m[10];
    inv[5]  =  m[0]*m[10]*m[15] - m[0]*m[11]*m[14] - m[8]*m[2]*m[15] + m[8]*m[3]*m[14] + m[12]*m[2]*m[11] - m[12]*m[3]*m[10];
    inv[9]  = -m[0]*m[9]*m[15]  + m[0]*m[11]*m[13] + m[8]*m[1]*m[15] - m[8]*m[3]*m[13] - m[12]*m[1]*m[11] + m[12]*m[3]*m[9];
    inv[13] =  m[0]*m[9]*m[14]  - m[0]*m[10]*m[13] - m[8]*m[1]*m[14] + m[8]*m[2]*m[13] + m[12]*m[1]*m[10] - m[12]*m[2]*m[9];
    inv[2]  =  m[1]*m[6]*m[15]  - m[1]*m[7]*m[14]  - m[5]*m[2]*m[15] + m[5]*m[3]*m[14] + m[13]*m[2]*m[7]  - m[13]*m[3]*m[6];
    inv[6]  = -m[0]*m[6]*m[15]  + m[0]*m[7]*m[14]  + m[4]*m[2]*m[15] - m[4]*m[3]*m[14] - m[12]*m[2]*m[7]  + m[12]*m[3]*m[6];
    inv[10] =  m[0]*m[5]*m[15]  - m[0]*m[7]*m[13]  - m[4]*m[1]*m[15] + m[4]*m[3]*m[13] + m[12]*m[1]*m[7]  - m[12]*m[3]*m[5];
    inv[14] = -m[0]*m[5]*m[14]  + m[0]*m[6]*m[13]  + m[4]*m[1]*m[14] - m[4]*m[2]*m[13] - m[12]*m[1]*m[6]  + m[12]*m[2]*m[5];
    inv[3]  = -m[1]*m[6]*m[11]  + m[1]*m[7]*m[10]  + m[5]*m[2]*m[11] - m[5]*m[3]*m[10] - m[9]*m[2]*m[7]   + m[9]*m[3]*m[6];
    inv[7]  =  m[0]*m[6]*m[11]  - m[0]*m[7]*m[10]  - m[4]*m[2]*m[11] + m[4]*m[3]*m[10] + m[8]*m[2]*m[7]   - m[8]*m[3]*m[6];
    inv[11] = -m[0]*m[5]*m[11]  + m[0]*m[7]*m[9]   + m[4]*m[1]*m[11] - m[4]*m[3]*m[9]  - m[8]*m[1]*m[7]   + m[8]*m[3]*m[5];
    inv[15] =  m[0]*m[5]*m[10]  - m[0]*m[6]*m[9]   - m[4]*m[1]*m[10] + m[4]*m[2]*m[9]  + m[8]*m[1]*m[6]   - m[8]*m[2]*m[5];
    float det = m[0]*inv[0] + m[1]*inv[4] + m[2]*inv[8] + m[3]*inv[12];
    float rd = 1.0f/det;
    for (int k = 0; k < 16; ++k) inv[k] *= rd;
}

// Per-batch params: P[b*24 + 0..8]=A1, [9..17]=A2, [18..20]=p0
__global__ void setup_k(const float* __restrict__ rt_inv, const float* __restrict__ k_inv,
                        const float* __restrict__ sdd,    const float* __restrict__ iso,
                        const float* __restrict__ affine, const float* __restrict__ rot,
                        const float* __restrict__ xyz,    float* __restrict__ P, int B)
{
    int b = blockIdx.x * blockDim.x + threadIdx.x;
    if (b >= B) return;

    const float* Mi = rt_inv + (size_t)b * 16;
    float rt[16];
    inv4x4(Mi, rt);

    float c[3];
    for (int r = 0; r < 3; ++r)
        c[r] = rt[r*4+0]*iso[0] + rt[r*4+1]*iso[1] + rt[r*4+2]*iso[2] + rt[r*4+3];

    float rx = rot[b*3+0], ry = rot[b*3+1], rz = rot[b*3+2];
    float th = sqrtf(rx*rx + ry*ry + rz*rz);
    float Rr[9];
    if (th < 1e-8f) {
        Rr[0]=1.f; Rr[1]=0.f; Rr[2]=0.f;
        Rr[3]=0.f; Rr[4]=1.f; Rr[5]=0.f;
        Rr[6]=0.f; Rr[7]=0.f; Rr[8]=1.f;
    } else {
        float kx = rx/th, ky = ry/th, kz = rz/th;
        float s = sinf(th), ct = cosf(th), v = 1.f - ct;
        Rr[0] = ct + v*kx*kx;     Rr[1] = v*kx*ky - s*kz;  Rr[2] = v*kx*kz + s*ky;
        Rr[3] = v*ky*kx + s*kz;   Rr[4] = ct + v*ky*ky;    Rr[5] = v*ky*kz - s*kx;
        Rr[6] = v*kz*kx - s*ky;   Rr[7] = v*kz*ky + s*kx;  Rr[8] = ct + v*kz*kz;
    }

    float tp[3];
    for (int r = 0; r < 3; ++r)
        tp[r] = c[r] + xyz[b*3+r] - (Rr[r*3+0]*c[0] + Rr[r*3+1]*c[1] + Rr[r*3+2]*c[2]);

    float G[9], t[3];
    for (int r = 0; r < 3; ++r) {
        for (int cc = 0; cc < 3; ++cc)
            G[r*3+cc] = Mi[r*4+0]*Rr[0*3+cc] + Mi[r*4+1]*Rr[1*3+cc] + Mi[r*4+2]*Rr[2*3+cc];
        t[r] = Mi[r*4+0]*tp[0] + Mi[r*4+1]*tp[1] + Mi[r*4+2]*tp[2] + Mi[r*4+3];
    }

    float Ai[16];
    inv4x4(affine, Ai);

    float p0[3];
    for (int r = 0; r < 3; ++r)
        p0[r] = Ai[r*4+0]*t[0] + Ai[r*4+1]*t[1] + Ai[r*4+2]*t[2] + Ai[r*4+3];

    float MG[9];
    for (int r = 0; r < 3; ++r)
        for (int cc = 0; cc < 3; ++cc)
            MG[r*3+cc] = Ai[r*4+0]*G[0*3+cc] + Ai[r*4+1]*G[1*3+cc] + Ai[r*4+2]*G[2*3+cc];

    const float* Ki = k_inv + (size_t)b * 9;
    float sd = sdd[b];
    float* Pb = P + (size_t)b * 24;
    for (int r = 0; r < 3; ++r)
        for (int cc = 0; cc < 3; ++cc) {
            Pb[r*3+cc]     = (MG[r*3+0]*Ki[0*3+cc] + MG[r*3+1]*Ki[1*3+cc] + MG[r*3+2]*Ki[2*3+cc]) * sd;
            Pb[9 + r*3+cc] = (G[r*3+0]*Ki[0*3+cc]  + G[r*3+1]*Ki[1*3+cc]  + G[r*3+2]*Ki[2*3+cc])  * sd;
        }
    Pb[18] = p0[0]; Pb[19] = p0[1]; Pb[20] = p0[2];
}

// 1 wave = 4 pixels (1x4 strip); lane = 16*p + t; lane t strides steps.
// Block (256 thr, 4 waves) owns a 4x4 pixel patch; 256 blocks = one 64x64
// supertile; supertiles chunked per XCD.
__global__ void __launch_bounds__(256, 6) drr8(
        const float* __restrict__ vol, const float* __restrict__ P,
        float* __restrict__ out,
        const int* __restrict__ Hp, const int* __restrict__ Wp, const int* __restrict__ Sp,
        int B, int D)
{
    const int H = *Hp, W = *Wp, S = *Sp;
    const int npix = H * W;
    const int nSj = (W + 63) >> 6, nSi = (H + 63) >> 6;
    const int nS = nSi * nSj;
    const int nStot = B * nS;
    const long long nVB = (long long)nStot << 8;   // 256 blocks per supertile

    const int tid  = threadIdx.x;
    const int wave = tid >> 6, lane = tid & 63;
    const int p    = lane >> 4, t = lane & 15;
    const int D1   = D - 1;
    const float Sf = (float)S, invS = 1.0f / Sf;

    for (long long vb = blockIdx.x; vb < nVB; vb += gridDim.x) {
        int st, within;
        if ((nStot & 7) == 0) {
            int xcd = (int)(vb & 7);
            long long slot = vb >> 3;
            st = xcd * (nStot >> 3) + (int)(slot >> 8);
            within = (int)(slot & 255);
        } else {
            st = (int)(vb >> 8);
            within = (int)(vb & 255);
        }
        int b = 0, stl = st;
        if (B > 1) { b = st / nS; stl = st - b * nS; }
        int si = stl / nSj, sj = stl - si * nSj;

        int r0 = (si << 6) + ((within >> 4) << 2) + wave;   // row
        int c0 = (sj << 6) + ((within & 15) << 2) + p;      // col
        bool valid = (r0 < H) && (c0 < W);
        int rr = min(r0, H - 1), cc = min(c0, W - 1);

        const float* Pb = P + 24 * __builtin_amdgcn_readfirstlane(b);
        float px = cc + 0.5f, py = rr + 0.5f;
        float ddx = fmaf(Pb[0], px, fmaf(Pb[1], py, Pb[2]));
        float ddy = fmaf(Pb[3], px, fmaf(Pb[4], py, Pb[5]));
        float ddz = fmaf(Pb[6], px, fmaf(Pb[7], py, Pb[8]));
        float rxx = fmaf(Pb[9], px, fmaf(Pb[10], py, Pb[11]));
        float ryy = fmaf(Pb[12], px, fmaf(Pb[13], py, Pb[14]));
        float rzz = fmaf(Pb[15], px, fmaf(Pb[16], py, Pb[17]));
        float p0x = Pb[18], p0y = Pb[19], p0z = Pb[20];

        float seglen = sqrtf(rxx*rxx + ryy*ryy + rzz*rzz) * invS;

        // slab clip to support box (-1, D), widened
        const float lo = -1.001f, hi = (float)D + 0.001f;
        float a0 = 0.f, a1 = 1.f;
        {
            float pp[3] = {p0x, p0y, p0z};
            float dd[3] = {ddx, ddy, ddz};
            #pragma unroll
            for (int ax = 0; ax < 3; ++ax) {
                if (fabsf(dd[ax]) > 1e-12f) {
                    float r  = 1.0f / dd[ax];
                    float t0 = (lo - pp[ax]) * r;
                    float t1 = (hi - pp[ax]) * r;
                    a0 = fmaxf(a0, fminf(t0, t1));
                    a1 = fminf(a1, fmaxf(t0, t1));
                } else if (pp[ax] < lo || pp[ax] > hi) {
                    a1 = -1.0f;
                }
            }
        }
        int slo = (int)ceilf(a0 * Sf - 0.5f) - 1;
        int shi = (int)floorf(a1 * Sf - 0.5f) + 1;
        if (slo < 0) slo = 0;
        if (shi > S - 1) shi = S - 1;

        float sum = 0.f;

        // ---- phase-split main block: 6 samples/thread ----
        {
            f2    q[24];
            float xs[6], ys[6], zs[6];

            #pragma unroll
            for (int it = 0; it < 6; ++it) {
                int s = slo + t + (it << 4);
                float al = (s + 0.5f) * invS;
                float x = fmaf(al, ddx, p0x);
                float y = fmaf(al, ddy, p0y);
                float z = fmaf(al, ddz, p0z);
                xs[it] = x; ys[it] = y; zs[it] = z;
                int ix = (int)floorf(x), iy = (int)floorf(y), iz = (int)floorf(z);
                int x0c = min(max(ix, 0), D1), x1c = min(max(ix + 1, 0), D1);
                int y0c = min(max(iy, 0), D1), y1c = min(max(iy + 1, 0), D1);
                int z0c = min(max(iz, 0), D - 2);
                int a0r = x0c * D, a1r = x1c * D;
                q[it*4+0] = *(const f2*)(vol + (unsigned)((a0r + y0c) * D + z0c));
                q[it*4+1] = *(const f2*)(vol + (unsigned)((a0r + y1c) * D + z0c));
                q[it*4+2] = *(const f2*)(vol + (unsigned)((a1r + y0c) * D + z0c));
                q[it*4+3] = *(const f2*)(vol + (unsigned)((a1r + y1c) * D + z0c));
            }

            #pragma unroll
            for (int it = 0; it < 6; ++it) {
                int s = slo + t + (it << 4);
                float act = (s <= shi) ? 1.0f : 0.0f;
                float x = xs[it], y = ys[it], z = zs[it];
                float fx = floorf(x), fy = floorf(y), fz = floorf(z);
                int ix = (int)fx, iy = (int)fy, iz = (int)fz;
                float tx = x - fx, ty = y - fy, tz = z - fz;
                int z0c = min(max(iz, 0), D - 2);
                bool e0 = (iz == z0c), em = (iz == z0c - 1), ep = (iz == z0c + 1);
                f2 q00 = q[it*4+0], q01 = q[it*4+1], q10 = q[it*4+2], q11 = q[it*4+3];
                float v0, v1, c00, c01, c10, c11;
                v0 = e0 ? q00.x : (ep ? q00.y : 0.f);
                v1 = e0 ? q00.y : (em ? q00.x : 0.f);
                c00 = fmaf(tz, v1 - v0, v0);
                v0 = e0 ? q01.x : (ep ? q01.y : 0.f);
                v1 = e0 ? q01.y : (em ? q01.x : 0.f);
                c01 = fmaf(tz, v1 - v0, v0);
                v0 = e0 ? q10.x : (ep ? q10.y : 0.f);
                v1 = e0 ? q10.y : (em ? q10.x : 0.f);
                c10 = fmaf(tz, v1 - v0, v0);
                v0 = e0 ? q11.x : (ep ? q11.y : 0.f);
                v1 = e0 ? q11.y : (em ? q11.x : 0.f);
                c11 = fmaf(tz, v1 - v0, v0);
                float wy0 = ((unsigned)iy       < (unsigned)D) ? 1.f - ty : 0.f;
                float wy1 = ((unsigned)(iy + 1) < (unsigned)D) ? ty       : 0.f;
                float wx0 = ((unsigned)ix       < (unsigned)D) ? 1.f - tx : 0.f;
                float wx1 = ((unsigned)(ix + 1) < (unsigned)D) ? tx       : 0.f;
                float s0 = fmaf(wy0, c00, wy1 * c01);
                float s1 = fmaf(wy0, c10, wy1 * c11);
                sum = fmaf(act * wx0, s0, sum);
                sum = fmaf(act * wx1, s1, sum);
            }
        }

        // generic tail (never taken for paths <= 96 steps)
        for (int s = slo + 96 + t; s <= shi; s += 16) {
            float al = (s + 0.5f) * invS;
            float x = fmaf(al, ddx, p0x);
            float y = fmaf(al, ddy, p0y);
            float z = fmaf(al, ddz, p0z);
            float fx = floorf(x), fy = floorf(y), fz = floorf(z);
            int ix = (int)fx, iy = (int)fy, iz = (int)fz;
            float tx = x - fx, ty = y - fy, tz = z - fz;
            int x0c = min(max(ix, 0), D1), x1c = min(max(ix + 1, 0), D1);
            int y0c = min(max(iy, 0), D1), y1c = min(max(iy + 1, 0), D1);
            int z0c = min(max(iz, 0), D - 2);
            int a0r = x0c * D, a1r = x1c * D;
            f2 q00 = *(const f2*)(vol + (unsigned)((a0r + y0c) * D + z0c));
            f2 q01 = *(const f2*)(vol + (unsigned)((a0r + y1c) * D + z0c));
            f2 q10 = *(const f2*)(vol + (unsigned)((a1r + y0c) * D + z0c));
            f2 q11 = *(const f2*)(vol + (unsigned)((a1r + y1c) * D + z0c));
            bool e0 = (iz == z0c), em = (iz == z0c - 1), ep = (iz == z0c + 1);
            float v0, v1, c00, c01, c10, c11;
            v0 = e0 ? q00.x : (ep ? q00.y : 0.f);
            v1 = e0 ? q00.y : (em ? q00.x : 0.f);
            c00 = fmaf(tz, v1 - v0, v0);
            v0 = e0 ? q01.x : (ep ? q01.y : 0.f);
            v1 = e0 ? q01.y : (em ? q01.x : 0.f);
            c01 = fmaf(tz, v1 - v0, v0);
            v0 = e0 ? q10.x : (ep ? q10.y : 0.f);
            v1 = e0 ? q10.y : (em ? q10.x : 0.f);
            c10 = fmaf(tz, v1 - v0, v0);
            v0 = e0 ? q11.x : (ep ? q11.y : 0.f);
            v1 = e0 ? q11.y : (em ? q11.x : 0.f);
            c11 = fmaf(tz, v1 - v0, v0);
            float wy0 = ((unsigned)iy       < (unsigned)D) ? 1.f - ty : 0.f;
            float wy1 = ((unsigned)(iy + 1) < (unsigned)D) ? ty       : 0.f;
            float wx0 = ((unsigned)ix       < (unsigned)D) ? 1.f - tx : 0.f;
            float wx1 = ((unsigned)(ix + 1) < (unsigned)D) ? tx       : 0.f;
            float s0 = fmaf(wy0, c00, wy1 * c01);
            float s1 = fmaf(wy0, c10, wy1 * c11);
            sum = fmaf(wx0, s0, sum);
            sum = fmaf(wx1, s1, sum);
        }

        sum += __shfl_xor(sum, 8, 16);
        sum += __shfl_xor(sum, 4, 16);
        sum += __shfl_xor(sum, 2, 16);
        sum += __shfl_xor(sum, 1, 16);

        if (t == 0 && valid)
            out[(size_t)b * npix + (size_t)rr * W + cc] = sum * seglen;
    }
}

extern "C" void kernel_launch(void* const* d_in, const int* in_sizes, int n_in,
                              void* d_out, int out_size, void* d_ws, size_t ws_size,
                              hipStream_t stream)
{
    const float* volume = (const float*)d_in[0];
    const float* rt_inv = (const float*)d_in[1];
    const float* k_inv  = (const float*)d_in[2];
    const float* sdd    = (const float*)d_in[3];
    const float* iso    = (const float*)d_in[4];
    const float* affine = (const float*)d_in[5];
    const float* rot    = (const float*)d_in[6];
    const float* xyz    = (const float*)d_in[7];
    const int*   Hp     = (const int*)d_in[8];
    const int*   Wp     = (const int*)d_in[9];
    const int*   Sp     = (const int*)d_in[10];

    int B = in_sizes[1] / 16;                         // rt_inv is (B,4,4)
    int D = (int)lroundf(cbrtf((float)in_sizes[0]));  // volume is (D,D,D)

    float* P = (float*)d_ws;
    setup_k<<<(B + 63) / 64, 64, 0, stream>>>(rt_inv, k_inv, sdd, iso, affine, rot, xyz, P, B);

    // one block per 4x4-pixel patch via device-side supertile walk
    long long hw = (long long)out_size / B;
    long long vbl = (long long)B * ((hw + 4095) >> 12) * 256;
    if (vbl > (1 << 22)) vbl = (1 << 22);
    drr8<<<(int)vbl, 256, 0, stream>>>(volume, P, (float*)d_out, Hp, Wp, Sp, B, D);
    (void)n_in; (void)ws_size;
}